// Round 2
// baseline (489.589 us; speedup 1.0000x reference)
//
#include <hip/hip_runtime.h>

// Problem constants (from reference setup_inputs)
#define BB 32     // batch
#define TD 256    // t_dim
#define HD 512    // h_dim
#define MM 128    // M (words)
#define NN 4096   // h*w

typedef __attribute__((ext_vector_type(8))) short short8;
typedef __attribute__((ext_vector_type(4))) float floatx4;

__device__ inline unsigned int bf16_rne(float f) {
    unsigned int u = __float_as_uint(f);
    return (u + 0x7fffu + ((u >> 16) & 1u)) >> 16;
}
__device__ inline float quad16_max(float v) {
    v = fmaxf(v, __shfl_xor(v, 1));
    v = fmaxf(v, __shfl_xor(v, 2));
    v = fmaxf(v, __shfl_xor(v, 4));
    v = fmaxf(v, __shfl_xor(v, 8));
    return v;
}
__device__ inline float quad16_sum(float v) {
    v += __shfl_xor(v, 1);
    v += __shfl_xor(v, 2);
    v += __shfl_xor(v, 4);
    v += __shfl_xor(v, 8);
    return v;
}

// async global->LDS, 16B per lane; LDS dest is wave-uniform base + lane*16.
__device__ __forceinline__ void gload16(const void* gptr, void* ldsptr) {
    __builtin_amdgcn_global_load_lds(
        (const __attribute__((address_space(1))) void*)gptr,
        (__attribute__((address_space(3))) void*)ldsptr,
        16, 0, 0);
}

// ---------------------------------------------------------------------------
// Kernel 1: Wp[b][h][m] = sum_t head_w[h][t] * W[b][t][m]  (fp32 GEMM, small)
// Emits MFMA-ready layouts:
//   Wpt_hi/Wpt_lo : bf16 [B][MM][HD]  (scores B-operand, h contiguous; hi=trunc16, lo=rne(x-hi))
//   Wp_b          : bf16 [B][HD][MM]  (PV B-operand, m contiguous, RNE)
// ---------------------------------------------------------------------------
__global__ __launch_bounds__(256, 2) void wp_kernel(
    const float* __restrict__ Wmat,     // [B][TD][MM]
    const float* __restrict__ head_w,   // [HD][TD]
    unsigned short* __restrict__ Wpt_hi,
    unsigned short* __restrict__ Wpt_lo,
    unsigned short* __restrict__ Wp_b)
{
    const int tid = threadIdx.x;
    const int tx = tid & 31;            // m group: m = tx*4 + c
    const int ty = tid >> 5;            // h group: h = ty*8 + r
    const int b  = blockIdx.y;
    const int h0 = blockIdx.x * 64;

    __shared__ float s_hw[64][64];      // [h][t]
    __shared__ float s_w[64][128];      // [t][m]

    float acc[8][4];
#pragma unroll
    for (int r = 0; r < 8; ++r)
#pragma unroll
        for (int c = 0; c < 4; ++c) acc[r][c] = 0.f;

    for (int t0 = 0; t0 < TD; t0 += 64) {
#pragma unroll
        for (int k = 0; k < 4; ++k) {
            int i = (tid >> 4) + 16 * k;
            int j = (tid & 15) * 4;
            *(float4*)&s_hw[i][j] = *(const float4*)&head_w[(h0 + i) * TD + t0 + j];
        }
#pragma unroll
        for (int k = 0; k < 8; ++k) {
            int i = (tid >> 5) + 8 * k;
            *(float4*)&s_w[i][(tid & 31) * 4] =
                *(const float4*)&Wmat[((b * TD) + t0 + i) * MM + (tid & 31) * 4];
        }
        __syncthreads();
#pragma unroll 4
        for (int tt = 0; tt < 64; ++tt) {
            float b4[4];
            *(float4*)b4 = *(const float4*)&s_w[tt][tx * 4];
#pragma unroll
            for (int r = 0; r < 8; ++r) {
                float a = s_hw[ty * 8 + r][tt];
#pragma unroll
                for (int c = 0; c < 4; ++c) acc[r][c] += a * b4[c];
            }
        }
        __syncthreads();
    }

    // ---- Wp_b store: bf16 [b][h][m], m contiguous ----
#pragma unroll
    for (int r = 0; r < 8; ++r) {
        unsigned int p0 = bf16_rne(acc[r][0]) | (bf16_rne(acc[r][1]) << 16);
        unsigned int p1 = bf16_rne(acc[r][2]) | (bf16_rne(acc[r][3]) << 16);
        uint2 v; v.x = p0; v.y = p1;
        *(uint2*)&Wp_b[((size_t)(b * HD) + h0 + ty * 8 + r) * MM + tx * 4] = v;
    }
    // ---- Wpt hi/lo store: bf16 [b][m][h], h contiguous (8 h per thread -> b128) ----
#pragma unroll
    for (int c = 0; c < 4; ++c) {
        unsigned int hw4[4], lw4[4];
#pragma unroll
        for (int rp = 0; rp < 4; ++rp) {
            float x0 = acc[2 * rp][c], x1 = acc[2 * rp + 1][c];
            unsigned int u0 = __float_as_uint(x0), u1 = __float_as_uint(x1);
            float l0 = x0 - __uint_as_float(u0 & 0xffff0000u);
            float l1 = x1 - __uint_as_float(u1 & 0xffff0000u);
            hw4[rp] = (u0 >> 16) | (u1 & 0xffff0000u);
            lw4[rp] = bf16_rne(l0) | (bf16_rne(l1) << 16);
        }
        size_t base = ((size_t)(b * MM) + tx * 4 + c) * HD + h0 + ty * 8;
        *(uint4*)&Wpt_hi[base] = make_uint4(hw4[0], hw4[1], hw4[2], hw4[3]);
        *(uint4*)&Wpt_lo[base] = make_uint4(lw4[0], lw4[1], lw4[2], lw4[3]);
    }
}

// ---------------------------------------------------------------------------
// Fused kernel: scores (bf16-split MFMA, K=512) -> softmax(M=128) -> PV (bf16
// MFMA, K=128) -> store out[h][n].  One block per (b, 128-row n-tile).
// 256 threads = 4 waves, 2x2 wave split in phase 1 (64n x 64m per wave).
//
// PIPELINE (round-1 race fixed):
//  - Phase 1: 16 chunks of K=32, tiles double-buffered in 64KB:
//      Ah[2] @0, Al[2] @16K, Bh[2] @32K, Bl[2] @48K (8KB each).
//    B staged by global_load_lds, PRE-SWIZZLED global source, linear LDS dest.
//    A staged via regs (fp32->bf16 hi/lo split), prefetched one chunk ahead.
//    Own-vmem drained BEFORE the barrier (cross-wave visibility), next
//    chunk's loads issued after it so they fly across the MFMA cluster.
//  - Phase 2: Wp_b double-buffered (2x16KB @32K/48K, As @0..32K).
//    RACE FIX vs round 1: counted wait moved BEFORE the barrier —
//    each wave certifies its OWN W(hc) slice pre-barrier; after the barrier
//    the whole tile is resident for every wave. vmcnt(8) leaves the previous
//    iteration's 8 output stores (and nothing else) in flight; stores are
//    never drained inside the loop.
//    In-order vmcnt bookkeeping at the wait of hc (oldest->newest):
//      stores(hc-2)[8], W(hc)[4], stores(hc-1)[8] -> vmcnt(8) retires
//      exactly through W(hc).  hc=0: only W(0) in flight -> vmcnt(0).
// ---------------------------------------------------------------------------
__global__ __launch_bounds__(256, 2) void fused_kernel(
    const float* __restrict__ H,              // [B][HD][NN]
    const unsigned short* __restrict__ Wpt_hi,// [B][MM][HD]
    const unsigned short* __restrict__ Wpt_lo,
    const unsigned short* __restrict__ Wp_b,  // [B][HD][MM]
    float* __restrict__ out)                  // [B][HD][NN]
{
    __shared__ __align__(16) unsigned char smem[65536];
    const int tid = threadIdx.x;
    const int w   = tid >> 6;
    const int L   = tid & 63;
    const int q   = L >> 4;
    const int l15 = L & 15;
    const int b   = blockIdx.y;
    const int n0  = blockIdx.x * 128;

    const int nh = (w & 1) * 64;        // wave n-half (phase 1 & 2)
    const int mh = (w >> 1) * 64;       // wave m-half (phase 1)

    const float* Hb = H + ((size_t)b * HD) * NN + n0;
    const unsigned short* WptH = Wpt_hi + (size_t)b * MM * HD;
    const unsigned short* WptL = Wpt_lo + (size_t)b * MM * HD;

    floatx4 acc[4][4];
#pragma unroll
    for (int nt = 0; nt < 4; ++nt)
#pragma unroll
        for (int mt = 0; mt < 4; ++mt) acc[nt][mt] = (floatx4){0.f, 0.f, 0.f, 0.f};

    // ---- staging coords ----
    const int sa_n = (w & 1) * 64 + L;   // n owned for A staging
    const int sa_h = (w >> 1) * 16;      // h-quarter within 32-h chunk
    const int u0   = (w >> 1) * 2;       // first h-unit owned

    int aw_off[2];                       // A LDS write offsets (invariant)
#pragma unroll
    for (int ii = 0; ii < 2; ++ii)
        aw_off[ii] = sa_n * 64 + (((u0 + ii) ^ (sa_n & 3)) * 16);

    int bg_off[2];                       // B gload per-lane global offsets (ushorts)
#pragma unroll
    for (int k = 0; k < 2; ++k) {
        int flat = tid + 256 * k;        // 0..511 = 128 m-rows x 4 units
        int m = flat >> 2, uu = flat & 3;
        bg_off[k] = m * HD + ((uu ^ (m & 3)) * 8);
    }
    const int wave_lds = (tid & 192) * 16;   // wave-uniform LDS slice base

    // ================= Phase 1: scores (16 chunks of K=32) =================
    float xa[16];
    const float* srcA = Hb + (size_t)sa_h * NN + sa_n;

    // prologue: chunk 0 in flight
#pragma unroll
    for (int k = 0; k < 2; ++k) {
        gload16(WptH + bg_off[k], smem + 32768 + wave_lds + 256 * 16 * k);
        gload16(WptL + bg_off[k], smem + 49152 + wave_lds + 256 * 16 * k);
    }
#pragma unroll
    for (int t = 0; t < 16; ++t) xa[t] = srcA[(size_t)t * NN];

#pragma unroll 1
    for (int c = 0; c < 16; ++c) {
        const int p = c & 1;
        unsigned char* AhP = smem + p * 8192;
        unsigned char* AlP = smem + 16384 + p * 8192;

        // --- convert + write A(c) (compiler waits the 16 xa loads) ---
#pragma unroll
        for (int ii = 0; ii < 2; ++ii) {
            unsigned int hp[4], lp[4];
#pragma unroll
            for (int jp = 0; jp < 4; ++jp) {
                float x0 = xa[ii * 8 + 2 * jp], x1 = xa[ii * 8 + 2 * jp + 1];
                unsigned int v0 = __float_as_uint(x0), v1 = __float_as_uint(x1);
                float l0 = x0 - __uint_as_float(v0 & 0xffff0000u);
                float l1 = x1 - __uint_as_float(v1 & 0xffff0000u);
                hp[jp] = (v0 >> 16) | (v1 & 0xffff0000u);
                lp[jp] = bf16_rne(l0) | (bf16_rne(l1) << 16);
            }
            *(uint4*)(AhP + aw_off[ii]) = make_uint4(hp[0], hp[1], hp[2], hp[3]);
            *(uint4*)(AlP + aw_off[ii]) = make_uint4(lp[0], lp[1], lp[2], lp[3]);
        }
        // own B(c) gloads + own A(c) ds_writes certified BEFORE the barrier
        asm volatile("s_waitcnt vmcnt(0) lgkmcnt(0)" ::: "memory");
        __builtin_amdgcn_s_barrier();
        __builtin_amdgcn_sched_barrier(0);

        // --- issue chunk c+1 (flies across the MFMA cluster below) ---
        if (c + 1 < 16) {
            const int h0n = 32 * (c + 1);
            unsigned char* BhN = smem + 32768 + (p ^ 1) * 8192;
            unsigned char* BlN = smem + 49152 + (p ^ 1) * 8192;
#pragma unroll
            for (int k = 0; k < 2; ++k) {
                gload16(WptH + h0n + bg_off[k], BhN + wave_lds + 256 * 16 * k);
                gload16(WptL + h0n + bg_off[k], BlN + wave_lds + 256 * 16 * k);
            }
            srcA += (size_t)32 * NN;
#pragma unroll
            for (int t = 0; t < 16; ++t) xa[t] = srcA[(size_t)t * NN];
        }

        // --- fragments + 48 MFMA on buffer p ---
        const unsigned char* BhP = smem + 32768 + p * 8192;
        const unsigned char* BlP = smem + 49152 + p * 8192;
        short8 ahf[4], alf[4], bhf[4], blf[4];
#pragma unroll
        for (int nt = 0; nt < 4; ++nt) {
            int n = nh + nt * 16 + l15;
            int off = n * 64 + ((q ^ (n & 3)) * 16);
            ahf[nt] = *(const short8*)(AhP + off);
            alf[nt] = *(const short8*)(AlP + off);
        }
#pragma unroll
        for (int mt = 0; mt < 4; ++mt) {
            int m = mh + mt * 16 + l15;
            int off = m * 64 + ((q ^ (m & 3)) * 16);
            bhf[mt] = *(const short8*)(BhP + off);
            blf[mt] = *(const short8*)(BlP + off);
        }
        __builtin_amdgcn_s_setprio(1);
#pragma unroll
        for (int nt = 0; nt < 4; ++nt)
#pragma unroll
            for (int mt = 0; mt < 4; ++mt) {
                acc[nt][mt] = __builtin_amdgcn_mfma_f32_16x16x32_bf16(ahf[nt], bhf[mt], acc[nt][mt], 0, 0, 0);
                acc[nt][mt] = __builtin_amdgcn_mfma_f32_16x16x32_bf16(alf[nt], bhf[mt], acc[nt][mt], 0, 0, 0);
                acc[nt][mt] = __builtin_amdgcn_mfma_f32_16x16x32_bf16(ahf[nt], blf[mt], acc[nt][mt], 0, 0, 0);
            }
        __builtin_amdgcn_s_setprio(0);
    }

    // ================= Softmax over m (128) =================
    // lane holds rows n = nh + nt*16 + q*4 + r, cols m = mh + mt*16 + l15
    float* redmax = (float*)(smem + 32768);          // [2][128] (Bh[0] area, dead)
    float* redsum = (float*)(smem + 32768 + 1024);   // [2][128]
    const int mhalf = w >> 1;

    float rmax[4][4];
#pragma unroll
    for (int nt = 0; nt < 4; ++nt)
#pragma unroll
        for (int r = 0; r < 4; ++r) {
            float v = fmaxf(fmaxf(acc[nt][0][r], acc[nt][1][r]),
                            fmaxf(acc[nt][2][r], acc[nt][3][r]));
            rmax[nt][r] = quad16_max(v);
        }
    if (l15 == 0) {
#pragma unroll
        for (int nt = 0; nt < 4; ++nt)
#pragma unroll
            for (int r = 0; r < 4; ++r)
                redmax[mhalf * 128 + nh + nt * 16 + q * 4 + r] = rmax[nt][r];
    }
    __syncthreads();
    float gmax[4][4], rsum[4][4];
#pragma unroll
    for (int nt = 0; nt < 4; ++nt)
#pragma unroll
        for (int r = 0; r < 4; ++r) {
            gmax[nt][r] = fmaxf(rmax[nt][r],
                                redmax[(1 - mhalf) * 128 + nh + nt * 16 + q * 4 + r]);
            float s = 0.f;
#pragma unroll
            for (int mt = 0; mt < 4; ++mt) {
                float e = __expf(acc[nt][mt][r] - gmax[nt][r]);
                acc[nt][mt][r] = e;
                s += e;
            }
            rsum[nt][r] = quad16_sum(s);
        }
    if (l15 == 0) {
#pragma unroll
        for (int nt = 0; nt < 4; ++nt)
#pragma unroll
            for (int r = 0; r < 4; ++r)
                redsum[mhalf * 128 + nh + nt * 16 + q * 4 + r] = rsum[nt][r];
    }
    __syncthreads();

    // write A_soft (bf16) to LDS [128n][16u] swizzled (reuses A buffers @0..32K)
    unsigned char* As = smem;
#pragma unroll
    for (int nt = 0; nt < 4; ++nt)
#pragma unroll
        for (int r = 0; r < 4; ++r) {
            int n = nh + nt * 16 + q * 4 + r;
            float inv = 1.f / (rsum[nt][r] + redsum[(1 - mhalf) * 128 + n]);
#pragma unroll
            for (int mt = 0; mt < 4; ++mt) {
                int m = mh + mt * 16 + l15;
                unsigned short v = (unsigned short)bf16_rne(acc[nt][mt][r] * inv);
                *(unsigned short*)(As + n * 256 + (((m >> 3) ^ (n & 15)) * 16) + (m & 7) * 2) = v;
            }
        }
    __syncthreads();

    // ================= Phase 2: PV (8 chunks of 64 h, double-buffered) ======
    const int hq = (w >> 1) * 32;
    const unsigned short* WpB = Wp_b + (size_t)b * HD * MM;
    float* outb = out + ((size_t)b * HD) * NN + n0;

    int wg_off[4];                       // Wp_b gload per-lane offsets (pre-swizzled)
#pragma unroll
    for (int k = 0; k < 4; ++k) {
        int flat = tid + 256 * k;        // 0..1023 = 64 h-rows x 16 units
        int hrow = flat >> 4, uu = flat & 15;
        wg_off[k] = hrow * MM + ((uu ^ (hrow & 15)) * 8);
    }
    // prologue: chunk 0 in flight
#pragma unroll
    for (int k = 0; k < 4; ++k)
        gload16(WpB + wg_off[k], smem + 32768 + wave_lds + 256 * 16 * k);

    // preload A-fragments (reused across all 8 h-chunks)
    short8 af[4][4];                     // [nt][ks]
#pragma unroll
    for (int nt = 0; nt < 4; ++nt)
#pragma unroll
        for (int ks = 0; ks < 4; ++ks) {
            int n = nh + nt * 16 + l15;
            af[nt][ks] = *(short8*)(As + n * 256 + (((q + 4 * ks) ^ (n & 15)) * 16));
        }

#pragma unroll 1
    for (int hc = 0; hc < 8; ++hc) {
        const int p = hc & 1;
        // retire OWN W(hc) slice BEFORE the barrier (cross-wave visibility).
        if (hc == 0) { asm volatile("s_waitcnt vmcnt(0)" ::: "memory"); }
        else         { asm volatile("s_waitcnt vmcnt(8)" ::: "memory"); }
        __builtin_amdgcn_sched_barrier(0);
        __builtin_amdgcn_s_barrier();
        __builtin_amdgcn_sched_barrier(0);
        // issue W(hc+1) into the other buffer; flies across the MFMA below.
        if (hc + 1 < 8) {
            const unsigned short* Wsrc = WpB + (size_t)(hc + 1) * 64 * MM;
            unsigned char* WbN = smem + 32768 + (p ^ 1) * 16384;
#pragma unroll
            for (int k = 0; k < 4; ++k)
                gload16(Wsrc + wg_off[k], WbN + wave_lds + 256 * 16 * k);
        }

        const unsigned char* WbP = smem + 32768 + p * 16384;
        floatx4 accB[4][2];
#pragma unroll
        for (int nt = 0; nt < 4; ++nt)
#pragma unroll
            for (int ht = 0; ht < 2; ++ht) accB[nt][ht] = (floatx4){0.f, 0.f, 0.f, 0.f};

#pragma unroll
        for (int ks = 0; ks < 4; ++ks) {
            short8 bf[2];
#pragma unroll
            for (int ht = 0; ht < 2; ++ht) {
                int hl = hq + ht * 16 + l15;
                bf[ht] = *(const short8*)(WbP + hl * 256 + (((q + 4 * ks) ^ (hl & 15)) * 16));
            }
#pragma unroll
            for (int nt = 0; nt < 4; ++nt)
#pragma unroll
                for (int ht = 0; ht < 2; ++ht)
                    accB[nt][ht] = __builtin_amdgcn_mfma_f32_16x16x32_bf16(af[nt][ks], bf[ht], accB[nt][ht], 0, 0, 0);
        }
        // store D[n][h] -> out[h][n]: lane = col h, 4 consecutive rows n -> float4
#pragma unroll
        for (int nt = 0; nt < 4; ++nt)
#pragma unroll
            for (int ht = 0; ht < 2; ++ht) {
                int hglob = hc * 64 + hq + ht * 16 + l15;
                int nrow = nh + nt * 16 + q * 4;
                *(floatx4*)(outb + (size_t)hglob * NN + nrow) = accB[nt][ht];
            }
    }
}

// ---------------------------------------------------------------------------
extern "C" void kernel_launch(void* const* d_in, const int* in_sizes, int n_in,
                              void* d_out, int out_size, void* d_ws, size_t ws_size,
                              hipStream_t stream)
{
    (void)in_sizes; (void)n_in; (void)out_size; (void)ws_size;
    const float* H      = (const float*)d_in[0];   // [32][512][64][64]
    const float* Wmat   = (const float*)d_in[1];   // [32][256][128]
    const float* head_w = (const float*)d_in[2];   // [512][256]
    float* out = (float*)d_out;                    // [32][512][64][64]

    // ws layout (12 MB total):
    unsigned short* Wpt_hi = (unsigned short*)d_ws;                    // 4 MB
    unsigned short* Wpt_lo = Wpt_hi + (size_t)BB * MM * HD;            // 4 MB
    unsigned short* Wp_b   = Wpt_lo + (size_t)BB * MM * HD;            // 4 MB

    wp_kernel<<<dim3(HD / 64, BB), 256, 0, stream>>>(Wmat, head_w, Wpt_hi, Wpt_lo, Wp_b);
    fused_kernel<<<dim3(NN / 128, BB), 256, 0, stream>>>(H, Wpt_hi, Wpt_lo, Wp_b, out);
}